// Round 3
// baseline (712.316 us; speedup 1.0000x reference)
//
#include <hip/hip_runtime.h>

#define NB   8
#define BKK  288
#define CWW  1152
#define HH   17
#define EPSF 1e-10f
#define ICH  8            // i-chunks for mstep partials
#define ISZ  (BKK/ICH)    // 36 i per chunk
#define JT   (CWW/64)     // 18 j-tiles of 64
#define SROWS 4           // i-rows per mpart batch
#define TF4  272          // float4 per 64-j tile (64*17/4)

// params per (b,j): [0..15]=mu, [16..31]=1/(2*sigsq), [32..47]=a*rsqrt(2pi)/(sig+eps)
// p12 per (b,j,chunk): [0..15]=s1[h], [16..31]=s2[h] ; p0 per (b,j,chunk): s0

__global__ __launch_bounds__(256) void mpart_kernel(
    const float* __restrict__ votes,
    const float* __restrict__ rt_in,     // null => iter0: rt = a_/32
    float* __restrict__ p12,
    float* __restrict__ p0)
{
    __shared__ float4 stage[2][SROWS * TF4];   // 2*1088*16 B = 34.8 KB
    __shared__ float  rtsh[2][SROWS * 64];

    const int bx = blockIdx.x;
    const int jt = bx % JT;
    const int t2 = bx / JT;
    const int c  = t2 % ICH;
    const int b  = t2 / ICH;

    const int t  = threadIdx.x;
    const int jl = t >> 2;
    const int h4 = t & 3;

    const size_t row0 = (size_t)(b * BKK + c * ISZ) * CWW;   // element row base, j=0
    const float4* vf4 = (const float4*)votes;
    const size_t base_f4 = (row0 * HH) >> 2;                 // divisible by 4 (proven)

    float4 ldv[5];
    float  ldrt;
    const int NQ = SROWS * TF4;                              // 1088

    auto load_batch = [&](int bt) {
        int i0 = bt * SROWS;
        #pragma unroll
        for (int u = 0; u < 5; u++) {
            int q = t + u * 256;
            if (q < NQ) {
                int r = q / TF4;
                int w = q - r * TF4;
                ldv[u] = vf4[base_f4 + (size_t)(i0 + r) * (CWW * HH / 4)
                                     + (size_t)jt * TF4 + w];
            }
        }
        if (rt_in) {
            int r = t >> 6, jj = t & 63;
            ldrt = rt_in[row0 + (size_t)(i0 + r) * CWW + jt * 64 + jj];
        }
    };
    auto write_batch = [&](int buf) {
        #pragma unroll
        for (int u = 0; u < 5; u++) {
            int q = t + u * 256;
            if (q < NQ) stage[buf][q] = ldv[u];
        }
        if (rt_in) rtsh[buf][t] = ldrt;
    };

    float s0 = 0.f;
    float s1[4] = {0.f, 0.f, 0.f, 0.f};
    float s2[4] = {0.f, 0.f, 0.f, 0.f};

    load_batch(0);
    write_batch(0);
    int buf = 0;
    const int NBATCH = ISZ / SROWS;   // 9
    for (int bt = 0; bt < NBATCH; bt++) {
        if (bt + 1 < NBATCH) load_batch(bt + 1);
        __syncthreads();
        const float* sb = (const float*)&stage[buf][0];
        #pragma unroll
        for (int r = 0; r < SROWS; r++) {
            const float* v = sb + r * (TF4 * 4) + jl * HH;
            float rt = rt_in ? rtsh[buf][r * 64 + jl] : v[16] * (1.f / 32.f);
            #pragma unroll
            for (int k = 0; k < 4; k++) {
                float vv = v[h4 * 4 + k];
                s1[k] += rt * vv;
                s2[k] += rt * vv * vv;
            }
            s0 += rt;
        }
        if (bt + 1 < NBATCH) write_batch(buf ^ 1);
        buf ^= 1;
    }

    const int j = jt * 64 + jl;
    float* o = p12 + (((size_t)(b * CWW + j)) * ICH + c) * 32 + h4 * 4;
    *(float4*)o        = make_float4(s1[0], s1[1], s1[2], s1[3]);
    *(float4*)(o + 16) = make_float4(s2[0], s2[1], s2[2], s2[3]);
    if (h4 == 0) p0[((size_t)(b * CWW + j)) * ICH + c] = s0;
}

__global__ __launch_bounds__(256) void mfin_kernel(
    const float* __restrict__ p12,
    const float* __restrict__ p0,
    const float* __restrict__ beta_v,
    const float* __restrict__ beta_a,
    float* __restrict__ params,          // non-final iters
    float* __restrict__ out_mua)         // final iter (params == null)
{
    const int wid  = (blockIdx.x * 256 + threadIdx.x) >> 6;   // bj = b*1152+j
    const int lane = threadIdx.x & 63;
    const int h    = lane & 15;
    const int q    = lane >> 4;
    const int b    = wid / CWW;
    const int j    = wid - b * CWW;

    float s0 = 0.f, s1 = 0.f, s2 = 0.f;
    #pragma unroll
    for (int cc = 0; cc < 2; cc++) {
        int c = q + cc * 4;
        const float* pp = p12 + ((size_t)wid * ICH + c) * 32;
        s1 += pp[h];
        s2 += pp[16 + h];
        s0 += p0[(size_t)wid * ICH + c];
    }
    s0 += __shfl_xor(s0, 16); s1 += __shfl_xor(s1, 16); s2 += __shfl_xor(s2, 16);
    s0 += __shfl_xor(s0, 32); s1 += __shfl_xor(s1, 32); s2 += __shfl_xor(s2, 32);

    float sumR  = s0 + 1e-4f;
    float mu    = s1 / sumR;
    float var   = s2 - 2.f * mu * s1 + mu * mu * s0 + EPSF * s0;
    var = fmaxf(var, 0.f);
    float sigsq = var / sumR + EPSF;
    float sig   = sqrtf(sigsq);
    float ls    = logf(sig + EPSF);
    float lssum = ls;
    lssum += __shfl_xor(lssum, 1);
    lssum += __shfl_xor(lssum, 2);
    lssum += __shfl_xor(lssum, 4);
    lssum += __shfl_xor(lssum, 8);
    const int c = j / 36;
    float cost = (16.f * beta_v[c] + lssum) * sumR;
    float aa   = 1.f / (1.f + expf(-1e-4f * (beta_a[c] - cost)));

    if (params) {
        if (q == 0) {
            float* p = params + (size_t)wid * 48;
            p[h]      = mu;
            p[16 + h] = 0.5f / sigsq;
            p[32 + h] = aa * 0.3989422804014327f / (sig + EPSF);
        }
    } else {
        float* o = out_mua + (size_t)wid * HH;
        if (q == 0) o[h] = mu;
        if (lane == 16) o[16] = aa;
    }
}

__global__ __launch_bounds__(256) void estep_kernel(
    const float* __restrict__ votes,
    const float* __restrict__ params,
    float* __restrict__ rt_out,          // Rt = (ap/(sum+eps)+eps)*a_
    float* __restrict__ copy_dst)        // non-null: stream votes row to out
{
    __shared__ float4 stage[2][TF4];     // 8.7 KB
    __shared__ float  apsh[CWW];
    __shared__ float  aash[CWW];
    __shared__ float  wred[4];

    const int bi = blockIdx.x;           // b*288+i
    const int b  = bi / BKK;
    const int t  = threadIdx.x;
    const int jl = t >> 2;
    const int h4 = t & 3;

    const float4* rowf4 = (const float4*)(votes + (size_t)bi * CWW * HH);
    float4* cpyf4 = copy_dst ? (float4*)(copy_dst + (size_t)bi * CWW * HH) : nullptr;
    const float* pb = params + (size_t)b * CWW * 48;

    float4 ld0, ld1;
    auto load_tile = [&](int tile) {
        ld0 = rowf4[(size_t)tile * TF4 + t];
        if (t < TF4 - 256) ld1 = rowf4[(size_t)tile * TF4 + 256 + t];
    };
    auto write_tile = [&](int tile, int buf) {
        stage[buf][t] = ld0;
        if (t < TF4 - 256) stage[buf][256 + t] = ld1;
        if (cpyf4) {
            cpyf4[(size_t)tile * TF4 + t] = ld0;
            if (t < TF4 - 256) cpyf4[(size_t)tile * TF4 + 256 + t] = ld1;
        }
    };

    float psum = 0.f;
    load_tile(0);
    write_tile(0, 0);
    int buf = 0;
    for (int tile = 0; tile < JT; tile++) {
        if (tile + 1 < JT) load_tile(tile + 1);
        __syncthreads();
        const float* v = (const float*)&stage[buf][0] + jl * HH;
        const int j = tile * 64 + jl;
        const float* pj4 = pb + (size_t)j * 48 + h4 * 4;
        float4 pm = *(const float4*)(pj4);
        float4 pi = *(const float4*)(pj4 + 16);
        float4 pw = *(const float4*)(pj4 + 32);
        float v0 = v[h4 * 4 + 0], v1 = v[h4 * 4 + 1];
        float v2 = v[h4 * 4 + 2], v3 = v[h4 * 4 + 3];
        float d, pj = 0.f;
        d = v0 - pm.x; pj += pw.x * __expf(-(d * d + EPSF) * pi.x);
        d = v1 - pm.y; pj += pw.y * __expf(-(d * d + EPSF) * pi.y);
        d = v2 - pm.z; pj += pw.z * __expf(-(d * d + EPSF) * pi.z);
        d = v3 - pm.w; pj += pw.w * __expf(-(d * d + EPSF) * pi.w);
        pj += __shfl_xor(pj, 1);
        pj += __shfl_xor(pj, 2);
        if (h4 == 0) {
            apsh[j] = pj;
            aash[j] = v[16];
            psum += pj;
        }
        if (tile + 1 < JT) write_tile(tile + 1, buf ^ 1);
        buf ^= 1;
    }

    for (int off = 32; off > 0; off >>= 1) psum += __shfl_down(psum, off);
    if ((t & 63) == 0) wred[t >> 6] = psum;
    __syncthreads();
    float inv = 1.f / ((wred[0] + wred[1] + wred[2] + wred[3]) + EPSF);

    for (int j = t; j < CWW; j += 256) {
        rt_out[(size_t)bi * CWW + j] = (apsh[j] * inv + EPSF) * aash[j];
    }
}

__global__ __launch_bounds__(256) void copy4_kernel(
    const float4* __restrict__ src, float4* __restrict__ dst, int n)
{
    int idx = blockIdx.x * 256 + threadIdx.x;
    if (idx < n) dst[idx] = src[idx];
}

extern "C" void kernel_launch(void* const* d_in, const int* in_sizes, int n_in,
                              void* d_out, int out_size, void* d_ws, size_t ws_size,
                              hipStream_t stream)
{
    const float* votes  = (const float*)d_in[0];
    const float* beta_v = (const float*)d_in[1];
    const float* beta_a = (const float*)d_in[2];
    float* out       = (float*)d_out;
    float* out_mua   = out;                                  // 8*1152*17 = 156672
    float* out_R     = out + (size_t)NB * CWW * HH;          // 8*288*1152 = 2654208
    float* out_votes = out_R + (size_t)NB * BKK * CWW;       // 45121536

    const size_t n_params = (size_t)NB * CWW * 48;
    const size_t n_p12    = (size_t)NB * CWW * ICH * 32;
    const size_t n_p0     = (size_t)NB * CWW * ICH;
    const size_t need     = (n_params + n_p12 + n_p0) * sizeof(float);

    float *params, *p12, *p0;
    bool fused;
    if (ws_size >= need) {
        params = (float*)d_ws;
        fused  = true;
    } else {
        params = out_votes;   // scratch in votes-out region; final copy overwrites
        fused  = false;
    }
    p12 = params + n_params;
    p0  = p12 + n_p12;

    dim3 blk(256);
    dim3 gmp(NB * ICH * JT); // 1152
    dim3 gmf(NB * CWW / 4);  // 2304
    dim3 ge(NB * BKK);       // 2304

    // iter 0
    mpart_kernel<<<gmp, blk, 0, stream>>>(votes, nullptr, p12, p0);
    mfin_kernel<<<gmf, blk, 0, stream>>>(p12, p0, beta_v, beta_a, params, nullptr);
    estep_kernel<<<ge, blk, 0, stream>>>(votes, params, out_R, nullptr);
    // iter 1
    mpart_kernel<<<gmp, blk, 0, stream>>>(votes, out_R, p12, p0);
    mfin_kernel<<<gmf, blk, 0, stream>>>(p12, p0, beta_v, beta_a, params, nullptr);
    estep_kernel<<<ge, blk, 0, stream>>>(votes, params, out_R,
                                         fused ? out_votes : nullptr);
    // iter 2 (final)
    mpart_kernel<<<gmp, blk, 0, stream>>>(votes, out_R, p12, p0);
    mfin_kernel<<<gmf, blk, 0, stream>>>(p12, p0, beta_v, beta_a, nullptr, out_mua);

    if (!fused) {
        int n4 = (int)((size_t)NB * BKK * CWW * HH / 4);
        copy4_kernel<<<dim3((n4 + 255) / 256), blk, 0, stream>>>(
            (const float4*)votes, (float4*)out_votes, n4);
    }
}

// Round 4
// 512.490 us; speedup vs baseline: 1.3899x; 1.3899x over previous
//
#include <hip/hip_runtime.h>

#define NB   8
#define BKK  288
#define CWW  1152
#define HH   17
#define EPSF 1e-10f
#define ICH  16           // i-chunks for mpart partials
#define ISZ  18           // BKK/ICH
#define JT   18           // CWW/64 j-tiles
#define ECH  8            // i-rows per estepA block
#define NECH 36           // BKK/ECH

// 4-aligned float4 (records are 17 floats, so 16B alignment is impossible;
// CDNA global dwordx4 only needs dword alignment)
struct __attribute__((aligned(4))) f4u { float x, y, z, w; };

// params per (b,j): [0..15]=mu, [16..31]=1/(2*sigsq), [32..47]=a*rsqrt(2pi)/(sig+eps)

__global__ __launch_bounds__(256) void mpart_kernel(
    const float* __restrict__ votes,
    const float* __restrict__ rt_in,     // null => iter0: rt = a_/32, write a_dense
    float* __restrict__ a_dense,
    float* __restrict__ p12,
    float* __restrict__ p0)
{
    const int x  = blockIdx.x;
    const int jt = x % JT;
    const int c  = (x / JT) % ICH;
    const int b  = x / (JT * ICH);
    const int t  = threadIdx.x;
    const int jl = t >> 2;               // 0..63 (j within tile)
    const int h4 = t & 3;                // h-quad
    const int i0 = c * ISZ;

    const size_t rowe = (size_t)CWW * HH;
    const float* base = votes + ((size_t)b * BKK + i0) * rowe + jt * (64 * HH);
    const int voff = jl * HH + h4 * 4;
    const int aoff = jl * HH + 16;

    float s0 = 0.f;
    float s1x=0.f,s1y=0.f,s1z=0.f,s1w=0.f;
    float s2x=0.f,s2y=0.f,s2z=0.f,s2w=0.f;

    if (rt_in == nullptr) {
        #pragma unroll 6
        for (int i = 0; i < ISZ; i++) {
            const float* rec = base + (size_t)i * rowe;
            f4u v = *(const f4u*)(rec + voff);
            float a16 = rec[aoff];
            float rt = a16 * (1.f / 32.f);
            s0 += rt;
            s1x += rt*v.x; s2x += rt*v.x*v.x;
            s1y += rt*v.y; s2y += rt*v.y*v.y;
            s1z += rt*v.z; s2z += rt*v.z*v.z;
            s1w += rt*v.w; s2w += rt*v.w*v.w;
            if (h4 == 0)
                a_dense[((size_t)b*BKK + i0 + i)*CWW + jt*64 + jl] = a16;
        }
    } else {
        const float* rb = rt_in + ((size_t)b*BKK + i0)*CWW + jt*64 + jl;
        #pragma unroll 6
        for (int i = 0; i < ISZ; i++) {
            const float* rec = base + (size_t)i * rowe;
            f4u v = *(const f4u*)(rec + voff);
            float rt = rb[(size_t)i * CWW];
            s0 += rt;
            s1x += rt*v.x; s2x += rt*v.x*v.x;
            s1y += rt*v.y; s2y += rt*v.y*v.y;
            s1z += rt*v.z; s2z += rt*v.z*v.z;
            s1w += rt*v.w; s2w += rt*v.w*v.w;
        }
    }

    const int j = jt * 64 + jl;
    float* o = p12 + (((size_t)(b * CWW + j)) * ICH + c) * 32 + h4 * 4;
    *(float4*)o        = make_float4(s1x, s1y, s1z, s1w);
    *(float4*)(o + 16) = make_float4(s2x, s2y, s2z, s2w);
    if (h4 == 0) p0[((size_t)(b * CWW + j)) * ICH + c] = s0;
}

__global__ __launch_bounds__(256) void mfin_kernel(
    const float* __restrict__ p12,
    const float* __restrict__ p0,
    const float* __restrict__ beta_v,
    const float* __restrict__ beta_a,
    float* __restrict__ params,          // non-final iters
    float* __restrict__ out_mua)         // final iter (params == null)
{
    const int wid  = (blockIdx.x * 256 + threadIdx.x) >> 6;   // b*1152+j
    const int lane = threadIdx.x & 63;
    const int h    = lane & 15;
    const int q    = lane >> 4;
    const int b    = wid / CWW;
    const int j    = wid - b * CWW;

    float s0 = 0.f, s1 = 0.f, s2 = 0.f;
    #pragma unroll
    for (int cc = 0; cc < 4; cc++) {
        int c = q * 4 + cc;
        const float* pp = p12 + ((size_t)wid * ICH + c) * 32;
        s1 += pp[h];
        s2 += pp[16 + h];
        s0 += p0[(size_t)wid * ICH + c];
    }
    s0 += __shfl_xor(s0, 16); s1 += __shfl_xor(s1, 16); s2 += __shfl_xor(s2, 16);
    s0 += __shfl_xor(s0, 32); s1 += __shfl_xor(s1, 32); s2 += __shfl_xor(s2, 32);

    float sumR  = s0 + 1e-4f;
    float mu    = s1 / sumR;
    float var   = s2 - 2.f * mu * s1 + mu * mu * s0 + EPSF * s0;
    var = fmaxf(var, 0.f);
    float sigsq = var / sumR + EPSF;
    float sig   = sqrtf(sigsq);
    float ls    = logf(sig + EPSF);
    float lssum = ls;
    lssum += __shfl_xor(lssum, 1);
    lssum += __shfl_xor(lssum, 2);
    lssum += __shfl_xor(lssum, 4);
    lssum += __shfl_xor(lssum, 8);
    const int c = j / 36;
    float cost = (16.f * beta_v[c] + lssum) * sumR;
    float aa   = 1.f / (1.f + expf(-1e-4f * (beta_a[c] - cost)));

    if (params) {
        if (q == 0) {
            float* p = params + (size_t)wid * 48;
            p[h]      = mu;
            p[16 + h] = 0.5f / sigsq;
            p[32 + h] = aa * 0.3989422804014327f / (sig + EPSF);
        }
    } else {
        float* o = out_mua + (size_t)wid * HH;
        if (q == 0) o[h] = mu;
        if (lane == 16) o[16] = aa;
    }
}

__global__ __launch_bounds__(256) void estepA_kernel(
    const float* __restrict__ votes,
    const float* __restrict__ params,
    float* __restrict__ p_arr,           // ap[b,i,j]
    float* __restrict__ psum,            // partial row sums [b,i,jt]
    float* __restrict__ copy_dst)        // non-null: stream votes to out
{
    __shared__ float wsum[4][ECH];
    const int x  = blockIdx.x;
    const int jt = x % JT;
    const int ic = (x / JT) % NECH;
    const int b  = x / (JT * NECH);
    const int t  = threadIdx.x;
    const int jl = t >> 2;
    const int h4 = t & 3;
    const int j  = jt * 64 + jl;
    const int i0 = ic * ECH;
    const int lane = t & 63, w = t >> 6;

    const float* pj4 = params + ((size_t)b * CWW + j) * 48 + h4 * 4;
    float4 pm = *(const float4*)(pj4);
    float4 pi = *(const float4*)(pj4 + 16);
    float4 pw = *(const float4*)(pj4 + 32);

    const size_t rowe = (size_t)CWW * HH;
    const float* base = votes + ((size_t)b * BKK + i0) * rowe + jt * (64 * HH);
    float* cbase = copy_dst ? copy_dst + ((size_t)b * BKK + i0) * rowe + jt * (64 * HH)
                            : nullptr;
    const int voff = jl * HH + h4 * 4;
    const int aoff = jl * HH + 16;

    #pragma unroll 4
    for (int i = 0; i < ECH; i++) {
        const float* rec = base + (size_t)i * rowe;
        f4u v = *(const f4u*)(rec + voff);
        float d, pj = 0.f;
        d = v.x - pm.x; pj += pw.x * __expf(-(d * d + EPSF) * pi.x);
        d = v.y - pm.y; pj += pw.y * __expf(-(d * d + EPSF) * pi.y);
        d = v.z - pm.z; pj += pw.z * __expf(-(d * d + EPSF) * pi.z);
        d = v.w - pm.w; pj += pw.w * __expf(-(d * d + EPSF) * pi.w);
        pj += __shfl_xor(pj, 1);
        pj += __shfl_xor(pj, 2);
        // all quad lanes now hold p(j); h4==0 writes
        if (h4 == 0)
            p_arr[((size_t)b * BKK + i0 + i) * CWW + j] = pj;
        if (cbase) {
            float* crec = cbase + (size_t)i * rowe;
            *(f4u*)(crec + voff) = v;
            if (h4 == 0) crec[aoff] = rec[aoff];
        }
        // wave-sum over the 16 jl (each j duplicated 4x, reduce jl bits only)
        float rs = pj;
        rs += __shfl_xor(rs, 4);
        rs += __shfl_xor(rs, 8);
        rs += __shfl_xor(rs, 16);
        rs += __shfl_xor(rs, 32);
        if (lane == 0) wsum[w][i] = rs;
    }
    __syncthreads();
    if (t < ECH) {
        float s = wsum[0][t] + wsum[1][t] + wsum[2][t] + wsum[3][t];
        psum[((size_t)b * BKK + i0 + t) * JT + jt] = s;
    }
}

__global__ __launch_bounds__(256) void estepB_kernel(
    const float* __restrict__ p_arr,
    const float* __restrict__ psum,
    const float* __restrict__ a_dense,
    float* __restrict__ rt_ws,           // (p/sum+eps)*a_  (next mpart input)
    float* __restrict__ r_out)           // optional: reference R = p/sum+eps
{
    const int bi = blockIdx.x;
    const int t  = threadIdx.x;
    const float* ps = psum + (size_t)bi * JT;
    float s = 0.f;
    #pragma unroll
    for (int k = 0; k < JT; k++) s += ps[k];
    float inv = 1.f / (s + EPSF);
    const size_t base = (size_t)bi * CWW;
    for (int j = t; j < CWW; j += 256) {
        float r = p_arr[base + j] * inv + EPSF;
        rt_ws[base + j] = r * a_dense[base + j];
        if (r_out) r_out[base + j] = r;
    }
}

__global__ __launch_bounds__(256) void copy4_kernel(
    const float4* __restrict__ src, float4* __restrict__ dst, int n)
{
    int idx = blockIdx.x * 256 + threadIdx.x;
    if (idx < n) dst[idx] = src[idx];
}

extern "C" void kernel_launch(void* const* d_in, const int* in_sizes, int n_in,
                              void* d_out, int out_size, void* d_ws, size_t ws_size,
                              hipStream_t stream)
{
    const float* votes  = (const float*)d_in[0];
    const float* beta_v = (const float*)d_in[1];
    const float* beta_a = (const float*)d_in[2];
    float* out       = (float*)d_out;
    float* out_mua   = out;                                  // 8*1152*17
    float* out_R     = out + (size_t)NB * CWW * HH;          // 8*288*1152
    float* out_votes = out_R + (size_t)NB * BKK * CWW;

    const size_t n_adense = (size_t)NB * BKK * CWW;          // 2654208
    const size_t n_rt     = n_adense;
    const size_t n_p      = n_adense;
    const size_t n_psum   = (size_t)NB * BKK * JT;           //   41472
    const size_t n_p12    = (size_t)NB * CWW * ICH * 32;     // 4718592
    const size_t n_p0     = (size_t)NB * CWW * ICH;          //  147456
    const size_t n_params = (size_t)NB * CWW * 48;           //  442368
    const size_t need = (n_adense + n_rt + n_p + n_psum + n_p12 + n_p0 + n_params)
                        * sizeof(float);

    float* scr;
    bool fused;
    if (ws_size >= need) { scr = (float*)d_ws; fused = true; }
    else                 { scr = out_votes;    fused = false; }  // copy4 overwrites last
    float* a_dense = scr;
    float* rt_ws   = a_dense + n_adense;
    float* p_arr   = rt_ws + n_rt;
    float* psum    = p_arr + n_p;
    float* p12     = psum + n_psum;
    float* p0      = p12 + n_p12;
    float* params  = p0 + n_p0;

    dim3 blk(256);
    dim3 gmp(NB * ICH * JT);   // 2304
    dim3 gmf(NB * CWW / 4);    // 2304
    dim3 gea(NB * NECH * JT);  // 5184
    dim3 geb(NB * BKK);        // 2304

    // iter 0
    mpart_kernel<<<gmp, blk, 0, stream>>>(votes, nullptr, a_dense, p12, p0);
    mfin_kernel<<<gmf, blk, 0, stream>>>(p12, p0, beta_v, beta_a, params, nullptr);
    estepA_kernel<<<gea, blk, 0, stream>>>(votes, params, p_arr, psum, nullptr);
    estepB_kernel<<<geb, blk, 0, stream>>>(p_arr, psum, a_dense, rt_ws, nullptr);
    // iter 1
    mpart_kernel<<<gmp, blk, 0, stream>>>(votes, rt_ws, a_dense, p12, p0);
    mfin_kernel<<<gmf, blk, 0, stream>>>(p12, p0, beta_v, beta_a, params, nullptr);
    estepA_kernel<<<gea, blk, 0, stream>>>(votes, params, p_arr, psum,
                                           fused ? out_votes : nullptr);
    estepB_kernel<<<geb, blk, 0, stream>>>(p_arr, psum, a_dense, rt_ws, out_R);
    // iter 2 (final)
    mpart_kernel<<<gmp, blk, 0, stream>>>(votes, rt_ws, a_dense, p12, p0);
    mfin_kernel<<<gmf, blk, 0, stream>>>(p12, p0, beta_v, beta_a, nullptr, out_mua);

    if (!fused) {
        int n4 = (int)((size_t)NB * BKK * CWW * HH / 4);
        copy4_kernel<<<dim3((n4 + 255) / 256), blk, 0, stream>>>(
            (const float4*)votes, (float4*)out_votes, n4);
    }
}

// Round 5
// 455.113 us; speedup vs baseline: 1.5651x; 1.1261x over previous
//
#include <hip/hip_runtime.h>

#define NB   8
#define BKK  288
#define CWW  1152
#define HH   17
#define EPSF 1e-10f
#define ICH  8            // i-chunks for mpart partials
#define ISZ  36           // BKK/ICH
#define JT   18           // CWW/64 j-tiles
#define ECH  8            // i-rows per estepA block
#define NECH 36           // BKK/ECH

// 4-aligned float4 (records are 17 floats; CDNA dwordx4 needs only dword align)
struct __attribute__((aligned(4))) f4u { float x, y, z, w; };
typedef float v4f __attribute__((ext_vector_type(4)));

// params per (b,j): [0..15]=mu, [16..31]=1/(2*sigsq), [32..47]=a*rsqrt(2pi)/(sig+eps)

__global__ __launch_bounds__(256) void mpart_kernel(
    const float* __restrict__ votes,
    const float* __restrict__ p_arr,     // null => iter0 (rt = a_/32)
    const float* __restrict__ rsinv,     // 1/(rowsum+eps) per (b,i)
    const float* __restrict__ a_dense,   // read (iters 1,2)
    float* __restrict__ a_out,           // write (iter0)
    float* __restrict__ p12,
    float* __restrict__ p0,
    float* __restrict__ r_out)           // iter2: R = p*rsinv+eps
{
    const int x  = blockIdx.x;
    const int jt = x % JT;
    const int c  = (x / JT) % ICH;
    const int b  = x / (JT * ICH);
    const int t  = threadIdx.x;
    const int jl = t >> 2;               // 0..63
    const int h4 = t & 3;
    const int i0 = c * ISZ;

    const size_t rowe = (size_t)CWW * HH;
    const float* base = votes + ((size_t)b * BKK + i0) * rowe + jt * (64 * HH);
    const int voff = jl * HH + h4 * 4;
    const int aoff = jl * HH + 16;
    const size_t dbase = ((size_t)b * BKK + i0) * CWW + jt * 64 + jl;
    const int bi0 = b * BKK + i0;

    float s0 = 0.f;
    float s1x=0.f,s1y=0.f,s1z=0.f,s1w=0.f;
    float s2x=0.f,s2y=0.f,s2z=0.f,s2w=0.f;

    if (p_arr == nullptr) {
        #pragma unroll 6
        for (int i = 0; i < ISZ; i++) {
            const float* rec = base + (size_t)i * rowe;
            f4u v = *(const f4u*)(rec + voff);
            float a16 = rec[aoff];
            float rt = a16 * (1.f / 32.f);
            s0 += rt;
            s1x += rt*v.x; s2x += rt*v.x*v.x;
            s1y += rt*v.y; s2y += rt*v.y*v.y;
            s1z += rt*v.z; s2z += rt*v.z*v.z;
            s1w += rt*v.w; s2w += rt*v.w*v.w;
            if (h4 == 0) a_out[dbase + (size_t)i * CWW] = a16;
        }
    } else {
        #pragma unroll 6
        for (int i = 0; i < ISZ; i++) {
            const float* rec = base + (size_t)i * rowe;
            f4u v = *(const f4u*)(rec + voff);
            float pv = p_arr[dbase + (size_t)i * CWW];
            float av = a_dense[dbase + (size_t)i * CWW];
            float ri = rsinv[bi0 + i];
            float rr = fmaf(pv, ri, EPSF);          // reference R
            float rt = rr * av;
            s0 += rt;
            s1x += rt*v.x; s2x += rt*v.x*v.x;
            s1y += rt*v.y; s2y += rt*v.y*v.y;
            s1z += rt*v.z; s2z += rt*v.z*v.z;
            s1w += rt*v.w; s2w += rt*v.w*v.w;
            if (r_out && h4 == 0)
                __builtin_nontemporal_store(rr, r_out + dbase + (size_t)i * CWW);
        }
    }

    const int j = jt * 64 + jl;
    float* o = p12 + (((size_t)(b * CWW + j)) * ICH + c) * 32 + h4 * 4;
    *(float4*)o        = make_float4(s1x, s1y, s1z, s1w);
    *(float4*)(o + 16) = make_float4(s2x, s2y, s2z, s2w);
    if (h4 == 0) p0[((size_t)(b * CWW + j)) * ICH + c] = s0;
}

__global__ __launch_bounds__(256) void mfin_kernel(
    const float* __restrict__ p12,
    const float* __restrict__ p0,
    const float* __restrict__ beta_v,
    const float* __restrict__ beta_a,
    float* __restrict__ params,          // non-final iters
    float* __restrict__ out_mua)         // final iter (params == null)
{
    const int wid  = (blockIdx.x * 256 + threadIdx.x) >> 6;   // b*1152+j
    const int lane = threadIdx.x & 63;
    const int h    = lane & 15;
    const int q    = lane >> 4;
    const int b    = wid / CWW;
    const int j    = wid - b * CWW;

    float s0 = 0.f, s1 = 0.f, s2 = 0.f;
    #pragma unroll
    for (int cc = 0; cc < ICH / 4; cc++) {
        int c = q + cc * 4;
        const float* pp = p12 + ((size_t)wid * ICH + c) * 32;
        s1 += pp[h];
        s2 += pp[16 + h];
        s0 += p0[(size_t)wid * ICH + c];
    }
    s0 += __shfl_xor(s0, 16); s1 += __shfl_xor(s1, 16); s2 += __shfl_xor(s2, 16);
    s0 += __shfl_xor(s0, 32); s1 += __shfl_xor(s1, 32); s2 += __shfl_xor(s2, 32);

    float sumR  = s0 + 1e-4f;
    float mu    = s1 / sumR;
    float var   = s2 - 2.f * mu * s1 + mu * mu * s0 + EPSF * s0;
    var = fmaxf(var, 0.f);
    float sigsq = var / sumR + EPSF;
    float sig   = sqrtf(sigsq);
    float ls    = logf(sig + EPSF);
    float lssum = ls;
    lssum += __shfl_xor(lssum, 1);
    lssum += __shfl_xor(lssum, 2);
    lssum += __shfl_xor(lssum, 4);
    lssum += __shfl_xor(lssum, 8);
    const int c = j / 36;
    float cost = (16.f * beta_v[c] + lssum) * sumR;
    float aa   = 1.f / (1.f + expf(-1e-4f * (beta_a[c] - cost)));

    if (params) {
        if (q == 0) {
            float* p = params + (size_t)wid * 48;
            p[h]      = mu;
            p[16 + h] = 0.5f / sigsq;
            p[32 + h] = aa * 0.3989422804014327f / (sig + EPSF);
        }
    } else {
        float* o = out_mua + (size_t)wid * HH;
        if (q == 0) o[h] = mu;
        if (lane == 16) o[16] = aa;
    }
}

__global__ __launch_bounds__(256) void estepA_kernel(
    const float* __restrict__ votes,
    const float* __restrict__ params,
    float* __restrict__ p_arr,           // p[b,i,j]
    float* __restrict__ psum,            // partial row sums [b,i,jt]
    float* __restrict__ copy_dst)        // non-null: stream votes to out (NT)
{
    __shared__ float wsum[4][ECH];
    const int x  = blockIdx.x;
    const int jt = x % JT;
    const int ic = (x / JT) % NECH;
    const int b  = x / (JT * NECH);
    const int t  = threadIdx.x;
    const int jl = t >> 2;
    const int h4 = t & 3;
    const int j  = jt * 64 + jl;
    const int i0 = ic * ECH;
    const int lane = t & 63, w = t >> 6;

    const float* pj4 = params + ((size_t)b * CWW + j) * 48 + h4 * 4;
    float4 pm = *(const float4*)(pj4);
    float4 pi = *(const float4*)(pj4 + 16);
    float4 pw = *(const float4*)(pj4 + 32);

    const size_t rowe = (size_t)CWW * HH;
    const float* base = votes + ((size_t)b * BKK + i0) * rowe + jt * (64 * HH);
    const int voff = jl * HH + h4 * 4;

    // aligned float4 view for the fused copy (tile base is 16B-aligned:
    // rowe*4 and 64*HH*4 are multiples of 16)
    const v4f* vt4 = (const v4f*)votes;
    v4f* ot4 = (v4f*)copy_dst;
    const size_t fb0 = (((size_t)b * BKK + i0) * rowe + jt * (64 * HH)) >> 2;

    #pragma unroll 4
    for (int i = 0; i < ECH; i++) {
        const float* rec = base + (size_t)i * rowe;
        f4u v = *(const f4u*)(rec + voff);
        float d, pj = 0.f;
        d = v.x - pm.x; pj += pw.x * __expf(-(d * d + EPSF) * pi.x);
        d = v.y - pm.y; pj += pw.y * __expf(-(d * d + EPSF) * pi.y);
        d = v.z - pm.z; pj += pw.z * __expf(-(d * d + EPSF) * pi.z);
        d = v.w - pm.w; pj += pw.w * __expf(-(d * d + EPSF) * pi.w);
        pj += __shfl_xor(pj, 1);
        pj += __shfl_xor(pj, 2);
        if (h4 == 0)
            p_arr[((size_t)b * BKK + i0 + i) * CWW + j] = pj;

        if (copy_dst) {   // aligned L1-hot re-read + NT store (272 f4/row)
            size_t fb = fb0 + (size_t)i * (rowe >> 2);
            v4f c0 = vt4[fb + t];
            __builtin_nontemporal_store(c0, ot4 + fb + t);
            if (t < 16) {
                v4f c1 = vt4[fb + 256 + t];
                __builtin_nontemporal_store(c1, ot4 + fb + 256 + t);
            }
        }

        float rs = pj;
        rs += __shfl_xor(rs, 4);
        rs += __shfl_xor(rs, 8);
        rs += __shfl_xor(rs, 16);
        rs += __shfl_xor(rs, 32);
        if (lane == 0) wsum[w][i] = rs;
    }
    __syncthreads();
    if (t < ECH) {
        float s = wsum[0][t] + wsum[1][t] + wsum[2][t] + wsum[3][t];
        psum[((size_t)b * BKK + i0 + t) * JT + jt] = s;
    }
}

__global__ __launch_bounds__(256) void rowsum_kernel(
    const float* __restrict__ psum, float* __restrict__ rsinv)
{
    int bi = blockIdx.x * 256 + threadIdx.x;
    if (bi < NB * BKK) {
        const float* ps = psum + (size_t)bi * JT;
        float s = 0.f;
        #pragma unroll
        for (int k = 0; k < JT; k++) s += ps[k];
        rsinv[bi] = 1.f / (s + EPSF);
    }
}

__global__ __launch_bounds__(256) void copy4_kernel(
    const float4* __restrict__ src, float4* __restrict__ dst, int n)
{
    int idx = blockIdx.x * 256 + threadIdx.x;
    if (idx < n) dst[idx] = src[idx];
}

extern "C" void kernel_launch(void* const* d_in, const int* in_sizes, int n_in,
                              void* d_out, int out_size, void* d_ws, size_t ws_size,
                              hipStream_t stream)
{
    const float* votes  = (const float*)d_in[0];
    const float* beta_v = (const float*)d_in[1];
    const float* beta_a = (const float*)d_in[2];
    float* out       = (float*)d_out;
    float* out_mua   = out;                                  // 8*1152*17
    float* out_R     = out + (size_t)NB * CWW * HH;          // 8*288*1152
    float* out_votes = out_R + (size_t)NB * BKK * CWW;

    const size_t n_adense = (size_t)NB * BKK * CWW;          // 2654208
    const size_t n_p      = n_adense;
    const size_t n_psum   = (size_t)NB * BKK * JT;
    const size_t n_rsinv  = (size_t)NB * BKK;
    const size_t n_p12    = (size_t)NB * CWW * ICH * 32;     // 2359296
    const size_t n_p0     = (size_t)NB * CWW * ICH;
    const size_t n_params = (size_t)NB * CWW * 48;
    const size_t need = (n_adense + n_p + n_psum + n_rsinv + n_p12 + n_p0 + n_params)
                        * sizeof(float);

    float* scr;
    bool fused;
    if (ws_size >= need) { scr = (float*)d_ws; fused = true; }
    else                 { scr = out_votes;    fused = false; }
    float* a_dense = scr;
    float* p_arr   = a_dense + n_adense;
    float* psum    = p_arr + n_p;
    float* rsinv   = psum + n_psum;
    float* p12     = rsinv + n_rsinv;
    float* p0      = p12 + n_p12;
    float* params  = p0 + n_p0;

    dim3 blk(256);
    dim3 gmp(NB * ICH * JT);   // 1152
    dim3 gmf(NB * CWW / 4);    // 2304
    dim3 gea(NB * NECH * JT);  // 5184
    dim3 grs((NB * BKK + 255) / 256);

    // iter 0
    mpart_kernel<<<gmp, blk, 0, stream>>>(votes, nullptr, nullptr, nullptr,
                                          a_dense, p12, p0, nullptr);
    mfin_kernel<<<gmf, blk, 0, stream>>>(p12, p0, beta_v, beta_a, params, nullptr);
    estepA_kernel<<<gea, blk, 0, stream>>>(votes, params, p_arr, psum, nullptr);
    rowsum_kernel<<<grs, blk, 0, stream>>>(psum, rsinv);
    // iter 1 (mpart computes rt inline from p, rsinv, a)
    mpart_kernel<<<gmp, blk, 0, stream>>>(votes, p_arr, rsinv, a_dense,
                                          nullptr, p12, p0, nullptr);
    mfin_kernel<<<gmf, blk, 0, stream>>>(p12, p0, beta_v, beta_a, params, nullptr);
    estepA_kernel<<<gea, blk, 0, stream>>>(votes, params, p_arr, psum,
                                           fused ? out_votes : nullptr);
    rowsum_kernel<<<grs, blk, 0, stream>>>(psum, rsinv);
    // iter 2 (final; also writes out_R = p*rsinv+eps)
    mpart_kernel<<<gmp, blk, 0, stream>>>(votes, p_arr, rsinv, a_dense,
                                          nullptr, p12, p0, out_R);
    mfin_kernel<<<gmf, blk, 0, stream>>>(p12, p0, beta_v, beta_a, nullptr, out_mua);

    if (!fused) {
        int n4 = (int)((size_t)NB * BKK * CWW * HH / 4);
        copy4_kernel<<<dim3((n4 + 255) / 256), blk, 0, stream>>>(
            (const float4*)votes, (float4*)out_votes, n4);
    }
}